// Round 8
// baseline (89.881 us; speedup 1.0000x reference)
//
#include <hip/hip_runtime.h>
#include <math.h>

// CTC loss (per-step-normalized fwd/bwd), B=128, C=512, T=512, S=128, L=257.
// Round-8: scan's per-lane row gathers (p1/p3: 64 distinct cache lines per
// instruction) are batched 4 columns at a time (float4) -> 4x fewer TA
// line-touches per step (the round-7 post-mortem's revised bottleneck model).
// Group-granular (8-step) double-buffered prefetch, compile-time component
// selection. Identity (validated r4-r7):
//   lh_t = sigma_i * D / (S_t * R_i), i = T-1-t,
//   D = sum_s' w_a[256-s',t] * U_i[s'],  U_i = masked shift of w_b row i-1,
//   S_t = sum w_a row t, R_i = sum w_b row i, sigma_i = 2^-e_g at i=8g.
// fp32 rows (136 MB -> L3-resident), fp64 log accumulation; logs clamped.

#define BB 128
#define CC 512
#define TT 512
#define SS 128
#define LL 257
#define LPAD 260    // floats per row (1040 B, 16B-aligned float4 at 4l)

// ---- fp32 DPP helpers (gfx9 controls; validated on gfx950 rounds 3-7) ----
template<int CTRL>
__device__ __forceinline__ float dpp0_f32(float x){
    int v = __builtin_bit_cast(int, x);
    int r = __builtin_amdgcn_update_dpp(0, v, CTRL, 0xF, 0xF, true);
    return __builtin_bit_cast(float, r);
}
__device__ __forceinline__ float shfl_up1_f32(float x){ return dpp0_f32<0x138>(x); }
__device__ __forceinline__ float red8f(float x){
    x += dpp0_f32<0x111>(x);  // row_shr:1
    x += dpp0_f32<0x112>(x);  // row_shr:2
    x += dpp0_f32<0x114>(x);  // row_shr:4
    return x;
}
__device__ __forceinline__ float tail3f(float x){   // full 64-lane sum -> lane 63
    x += dpp0_f32<0x118>(x);  // row_shr:8
    x += dpp0_f32<0x142>(x);  // row_bcast:15
    x += dpp0_f32<0x143>(x);  // row_bcast:31
    return x;
}
__device__ __forceinline__ float full64f(float x){ return tail3f(red8f(x)); }
__device__ __forceinline__ float readlane63_f32(float x){
    int v = __builtin_bit_cast(int, x);
    return __builtin_bit_cast(float, __builtin_amdgcn_readlane(v, 63));
}
__device__ __forceinline__ float pow2if(int e){     // e in [-126,127], exact
    return __builtin_bit_cast(float, (127 + e) << 23);
}
// ---- fp64 DPP (final reductions only) ----
template<int CTRL>
__device__ __forceinline__ double dpp0_f64(double x){
    int2 v = __builtin_bit_cast(int2, x);
    int2 r;
    r.x = __builtin_amdgcn_update_dpp(0, v.x, CTRL, 0xF, 0xF, true);
    r.y = __builtin_amdgcn_update_dpp(0, v.y, CTRL, 0xF, 0xF, true);
    return __builtin_bit_cast(double, r);
}
__device__ __forceinline__ double full64d(double x){
    x += dpp0_f64<0x111>(x); x += dpp0_f64<0x112>(x); x += dpp0_f64<0x114>(x);
    x += dpp0_f64<0x118>(x); x += dpp0_f64<0x142>(x); x += dpp0_f64<0x143>(x);
    return x;
}

// =================== row-storing scan (both roles, fp32) ===================
template<bool REV>
__device__ __forceinline__ void scan_body(
    int b, int l, const float* __restrict__ P, const int* __restrict__ seqg,
    int blank, float* __restrict__ W, int* __restrict__ Eb)
{
    const bool is63 = (l == 63);
    const float* Pb = P + (size_t)b * (CC*TT);
    const int* sq = seqg + b*SS;

    int r1, r3; float m1, m3;
    if (!REV) {
        r1 = sq[2*l]; r3 = sq[2*l+1];
        int ip = (l==0) ? 0 : (2*l-1);
        m1 = (l==0) ? 1.f : ((r1 != sq[ip]) ? 1.f : 0.f);
        m3 = (r3 != r1) ? 1.f : 0.f;
    } else {
        r1 = sq[SS-1-2*l]; r3 = sq[SS-2-2*l];
        int ip = (l==0) ? 0 : (SS-2*l);
        m1 = (l==0) ? 1.f : ((r1 != sq[ip]) ? 1.f : 0.f);
        m3 = (r3 != r1) ? 1.f : 0.f;
    }
    const float* pBp = Pb + (size_t)blank*TT;
    const float* p1p = Pb + (size_t)r1*TT;
    const float* p3p = Pb + (size_t)r3*TT;
    float* Ww = W + (size_t)b*TT*LPAD;
    int* EbB = Eb + b*64;

    // start-mask thresholds: state s masked at step i iff i >= (s+769)>>1
    const int tm0=(4*l+769)>>1, tm1=(4*l+770)>>1, tm2=(4*l+771)>>1, tm3=(4*l+772)>>1;

    float a0=0.f,a1=0.f,a2=0.f,a3=0.f,a4=0.f;
    float scNext = 1.f, Sfull = 0.f;
    const float u0i = (l==0) ? 1.f : 0.f;
    // group store buffer (static-indexed -> registers)
    float sb0[8], sb1[8], sb2[8], sb3[8], s4[8];
    // group-batched p columns: [half] covers steps j=0..3 / 4..7 of the group
    float4 curB[2], cur1[2], cur3[2], nxtB[2], nxt1[2], nxt3[2];

// load the two float4 column-chunks of group starting at step i0
#define LDG(i0, dB, d1, d3)                                                 \
  {                                                                         \
    const int c0 = REV ? (TT-4-(i0)) : (i0);                                \
    const int c1 = REV ? (TT-8-(i0)) : ((i0)+4);                            \
    dB[0] = *reinterpret_cast<const float4*>(pBp + c0);                     \
    dB[1] = *reinterpret_cast<const float4*>(pBp + c1);                     \
    d1[0] = *reinterpret_cast<const float4*>(p1p + c0);                     \
    d1[1] = *reinterpret_cast<const float4*>(p1p + c1);                     \
    d3[0] = *reinterpret_cast<const float4*>(p3p + c0);                     \
    d3[1] = *reinterpret_cast<const float4*>(p3p + c1);                     \
  }
#define CPY                                                                 \
  { curB[0]=nxtB[0]; curB[1]=nxtB[1]; cur1[0]=nxt1[0]; cur1[1]=nxt1[1];     \
    cur3[0]=nxt3[0]; cur3[1]=nxt3[1]; }
// component select; c is compile-time after unroll
#define COMPX(v,c) ((c)==0?(v).x:((c)==1?(v).y:((c)==2?(v).z:(v).w)))

#define STEP(i, j, FIRSTF, MASKF)                                           \
  {                                                                         \
    float u0,u1,u2,u3,u4;                                                   \
    if (FIRSTF) { u0=u0i; u1=u0i; u2=0.f; u3=0.f; u4=0.f; }                 \
    else {                                                                  \
      float e3u = shfl_up1_f32(a3);                                         \
      u0 = a0 + e3u; u1 = (a1+a0) + m1*e3u; u2 = a2+a1;                     \
      u3 = (a3+a2) + m3*a1; u4 = a4+a3;                                     \
      if (MASKF) {                                                          \
        if ((i) >= tm0) u0 = 0.f;                                           \
        if ((i) >= tm1) u1 = 0.f;                                           \
        if ((i) >= tm2) u2 = 0.f;                                           \
        if ((i) >= tm3) u3 = 0.f;                                           \
      }                                                                     \
    }                                                                       \
    const int hlf = (j)>>2;                                                 \
    const int cmp = REV ? (3-((j)&3)) : ((j)&3);                            \
    float pB = COMPX(curB[hlf], cmp);                                       \
    float pq = COMPX(cur1[hlf], cmp);                                       \
    float pr = COMPX(cur3[hlf], cmp);                                       \
    if ((j)==0) { pB*=scNext; pq*=scNext; pr*=scNext; }                     \
    float n0=u0*pB, n1=u1*pq, n2=u2*pB, n3=u3*pr, n4=u4*pB;                 \
    sb0[j]=n0; sb1[j]=n1; sb2[j]=n2; sb3[j]=n3; s4[j]=n4;                   \
    if ((j)==5) {                                                           \
      float part=(n0+n1)+(n2+n3); if (is63) part+=n4;                       \
      Sfull = full64f(part);                                                \
    }                                                                       \
    if ((j)==7) {                                                           \
      float Su = readlane63_f32(Sfull);                                     \
      int ex = (__builtin_bit_cast(int, Su) >> 23) & 0xFF;                  \
      int e = (ex==0) ? 0 : (ex-127);                                       \
      e = e < -120 ? -120 : (e > 120 ? 120 : e);                            \
      scNext = pow2if(-e);                                                  \
      if (REV && l==0 && (i)+1 < TT) EbB[((i)+1)>>3] = e;                   \
    }                                                                       \
    a0=n0; a1=n1; a2=n2; a3=n3; a4=n4;                                      \
  }

#define GSTORE                                                              \
  {                                                                         \
    _Pragma("unroll")                                                       \
    for (int j=0;j<8;++j)                                                   \
      *reinterpret_cast<float4*>(Ww + (size_t)j*LPAD + 4*l)                 \
          = make_float4(sb0[j],sb1[j],sb2[j],sb3[j]);                       \
    if (is63) {                                                             \
      _Pragma("unroll")                                                     \
      for (int j=0;j<8;++j) Ww[(size_t)j*LPAD + 256] = s4[j];               \
    }                                                                       \
    Ww += 8*LPAD;                                                           \
  }

    LDG(0, curB, cur1, cur3)
    LDG(8, nxtB, nxt1, nxt3)

    // group 0 (init row at i=0; no mask possible before i=384)
    STEP(0,0,true,false)  STEP(1,1,false,false) STEP(2,2,false,false)
    STEP(3,3,false,false) STEP(4,4,false,false) STEP(5,5,false,false)
    STEP(6,6,false,false) STEP(7,7,false,false)
    GSTORE
    CPY
    LDG(16, nxtB, nxt1, nxt3)

    for (int i0=8; i0<TT-SS; i0+=8) {
        #pragma unroll
        for (int j=0;j<8;++j) STEP(i0+j, j, false, false)
        GSTORE
        CPY
        const int nx = (i0+16 <= TT-8) ? (i0+16) : (TT-8);
        LDG(nx, nxtB, nxt1, nxt3)
    }
    for (int i0=TT-SS; i0<TT; i0+=8) {
        #pragma unroll
        for (int j=0;j<8;++j) STEP(i0+j, j, false, true)
        GSTORE
        CPY
        const int nx = (i0+16 <= TT-8) ? (i0+16) : (TT-8);
        LDG(nx, nxtB, nxt1, nxt3)
    }
#undef STEP
#undef GSTORE
#undef LDG
#undef CPY
#undef COMPX
}

__global__ __launch_bounds__(64)
void ctc_scan(const float* __restrict__ P, const int* __restrict__ seqg,
              const int* __restrict__ blankp, float* __restrict__ Wa,
              float* __restrict__ Wb, int* __restrict__ Eb)
{
    const int bx = blockIdx.x, l = threadIdx.x;
    const int blank = blankp[0];
    if (bx < BB) scan_body<false>(bx,      l, P, seqg, blank, Wa, Eb);
    else         scan_body<true >(bx - BB, l, P, seqg, blank, Wb, Eb);
}

// =========================== parallel combine ===========================
// Block (b, q): one wave handles t = 8q .. 8q+7.  i = T-1-t.
__global__ __launch_bounds__(64)
void ctc_combine(const float* __restrict__ Wa, const float* __restrict__ Wb,
                 const int* __restrict__ Eb, const int* __restrict__ seqg,
                 double* __restrict__ Lq)
{
    const int b = blockIdx.x, q = blockIdx.y, l = threadIdx.x;
    const bool is63 = (l == 63);
    const int* sq = seqg + b*SS;
    // beta-orientation skip masks (same as the beta scan)
    const int r1 = sq[SS-1-2*l], r3 = sq[SS-2-2*l];
    const int ip = (l==0) ? 0 : (SS-2*l);
    const float m1 = (l==0) ? 1.f : ((r1 != sq[ip]) ? 1.f : 0.f);
    const float m3 = (r3 != r1) ? 1.f : 0.f;
    const int tm0=(4*l+769)>>1, tm1=(4*l+770)>>1, tm2=(4*l+771)>>1, tm3=(4*l+772)>>1;

    const float* WaB = Wa + (size_t)b*TT*LPAD;
    const float* WbB = Wb + (size_t)b*TT*LPAD;
    const int t0 = q*8;

    // preload R for the first step: R_i0 = sum of w_b row i0 = T-1-t0
    float Rcur;
    {
        const float* rw = WbB + (size_t)(TT-1-t0)*LPAD;
        float4 x = *reinterpret_cast<const float4*>(rw + 4*l);
        float rnp = (x.x+x.y)+(x.z+x.w);
        if (is63) rnp += rw[256];
        Rcur = full64f(rnp);          // valid on lane 63 (consumed there)
    }
    double acc = 0.0;

    #pragma unroll
    for (int k=0; k<8; ++k) {
        const int t = t0 + k;
        const int i = TT-1-t;
        // alpha row t, reversed fragment: lane l holds w_a[252-4l .. 255-4l];
        // the 5th element w_a[256-4l] = neighbor's av.x (DPP), lane0 = row[256]
        const float* arow = WaB + (size_t)t*LPAD;
        float4 av = *reinterpret_cast<const float4*>(arow + (252 - 4*l));
        float a256 = arow[256];                     // uniform
        float ar4 = shfl_up1_f32(av.x);
        if (l == 0) ar4 = a256;

        float u0,u1,u2,u3,u4, rnext = 0.f;
        if (i > 0) {
            const float* rw = WbB + (size_t)(i-1)*LPAD;
            float4 bv = *reinterpret_cast<const float4*>(rw + 4*l);
            float b4 = rw[256];                     // uniform broadcast
            float e3u = shfl_up1_f32(bv.w);         // w_b[4l-1]
            u0 = bv.x + e3u;
            u1 = (bv.y + bv.x) + m1*e3u;
            u2 = bv.z + bv.y;
            u3 = (bv.w + bv.z) + m3*bv.y;
            u4 = b4 + bv.w;                         // s'=256 (lane 63)
            if (i >= TT - SS) {
                if (i >= tm0) u0 = 0.f;
                if (i >= tm1) u1 = 0.f;
                if (i >= tm2) u2 = 0.f;
                if (i >= tm3) u3 = 0.f;
            }
            rnext = (bv.x+bv.y)+(bv.z+bv.w);        // R_{i-1} partial
            if (is63) rnext += b4;
        } else {
            u0 = (l==0)?1.f:0.f; u1 = u0; u2=0.f; u3=0.f; u4=0.f;
        }
        // D = sum_s' w_a[256-s',t]*U[s'] ; S = sum w_a row t
        float trp = ar4*u0 + av.w*u1 + av.z*u2 + av.y*u3;
        if (is63) trp += av.x*u4;
        float sap = (av.y + av.z) + (av.w + ar4);
        if (is63) sap += av.x;

        float D  = full64f(trp);
        float S  = full64f(sap);
        float Rn = full64f(rnext);
        if (is63) {
            double e = (i > 0 && (i & 7) == 0) ? (double)Eb[b*64 + (i>>3)] : 0.0;
            double dd = fmax((double)D, 1e-300);
            double sr = fmax((double)S * (double)Rcur, 1e-300);
            acc += log(dd) - log(sr) - e*M_LN2;
        }
        Rcur = Rn;   // lane-63-valid, lane-63-consumed
    }
    if (is63) Lq[b*64 + q] = acc;
}

__global__ __launch_bounds__(256)
void ctc_final(const double* __restrict__ Lq, float* __restrict__ out)
{
    const int t = threadIdx.x;        // 256 threads, 8192 inputs
    double v = 0.0;
    #pragma unroll
    for (int k=0;k<32;++k) v += Lq[t + 256*k];
    double s = full64d(v);
    __shared__ double w[4];
    if ((t & 63) == 63) w[t>>6] = s;
    __syncthreads();
    if (t == 0) out[0] = (float)(-(w[0]+w[1]+w[2]+w[3]));
}

extern "C" void kernel_launch(void* const* d_in, const int* in_sizes, int n_in,
                              void* d_out, int out_size, void* d_ws, size_t ws_size,
                              hipStream_t stream)
{
    const float* P     = (const float*)d_in[0];   // params (B,C,T) fp32
    const int*   seq   = (const int*)  d_in[1];   // (B,S) int32
    // d_in[2] = lengths (unused by the reference computation)
    const int*   blank = (const int*)  d_in[3];   // scalar int

    // ws layout: Wa rows (68.2 MB) | Wb rows (68.2 MB) | Lq | Eb  (~136.5 MB)
    float* Wa = (float*)d_ws;
    float* Wb = Wa + (size_t)BB*TT*LPAD;
    double* Lq = (double*)(Wb + (size_t)BB*TT*LPAD);   // 8192 doubles
    int*    Eb = (int*)(Lq + (size_t)BB*64);           // 8192 ints
    (void)ws_size; (void)in_sizes; (void)n_in; (void)out_size;

    ctc_scan<<<2*BB, 64, 0, stream>>>(P, seq, blank, Wa, Wb, Eb);
    ctc_combine<<<dim3(BB, 64), 64, 0, stream>>>(Wa, Wb, Eb, seq, Lq);
    ctc_final<<<1, 256, 0, stream>>>(Lq, (float*)d_out);
}

// Round 9
// 79.607 us; speedup vs baseline: 1.1291x; 1.1291x over previous
//
#include <hip/hip_runtime.h>
#include <math.h>

// CTC loss (per-step-normalized fwd/bwd), B=128, C=512, T=512, S=128, L=257.
// Round-9: rows stored as BF16 (truncated fp32; recursion stays fp32 in regs).
//  - bf16 (not fp16): within-group dynamic range ~2^55 needs fp32 exponent range.
//  - truncation bias cancels to 1st order in lh = D/(S*R) (same-biased bilinear
//    sums in numerator and denominator).
//  - row buffers 34 MB each (both = 68 MB, deep inside L3); scan writes and
//    combine reads halve vs round 6-8.
//  - s=256 edge element moved to compact side arrays W4a/W4b (one packed
//    dwordx4 store per 8-step group instead of 8 scalar stores).
// Identity (validated r4-r8):  lh_t = sigma_i * D / (S_t * R_i), i = T-1-t,
//   D = sum_s' w_a[256-s',t] * U_i[s'],  U_i = masked shift of w_b row i-1,
//   S_t = sum w_a row t, R_i = sum w_b row i, sigma_i = 2^-e_g at i=8g.
// All quantities >= 0 and finite; logs clamped -> no NaN possible.

#define BB 128
#define CC 512
#define TT 512
#define SS 128
#define LL 257
#define LPADH 260   // bf16 (ushort) elements per row = 520 B, 8B-aligned slots

typedef unsigned int  uint;
typedef unsigned short ushort;

// ---- fp32 DPP helpers (gfx9 controls; validated on gfx950 rounds 3-8) ----
template<int CTRL>
__device__ __forceinline__ float dpp0_f32(float x){
    int v = __builtin_bit_cast(int, x);
    int r = __builtin_amdgcn_update_dpp(0, v, CTRL, 0xF, 0xF, true);
    return __builtin_bit_cast(float, r);
}
__device__ __forceinline__ float shfl_up1_f32(float x){ return dpp0_f32<0x138>(x); }
__device__ __forceinline__ float red8f(float x){
    x += dpp0_f32<0x111>(x);  // row_shr:1
    x += dpp0_f32<0x112>(x);  // row_shr:2
    x += dpp0_f32<0x114>(x);  // row_shr:4
    return x;
}
__device__ __forceinline__ float tail3f(float x){   // full 64-lane sum -> lane 63
    x += dpp0_f32<0x118>(x);  // row_shr:8
    x += dpp0_f32<0x142>(x);  // row_bcast:15
    x += dpp0_f32<0x143>(x);  // row_bcast:31
    return x;
}
__device__ __forceinline__ float full64f(float x){ return tail3f(red8f(x)); }
__device__ __forceinline__ float readlane63_f32(float x){
    int v = __builtin_bit_cast(int, x);
    return __builtin_bit_cast(float, __builtin_amdgcn_readlane(v, 63));
}
__device__ __forceinline__ float pow2if(int e){     // e in [-126,127], exact
    return __builtin_bit_cast(float, (127 + e) << 23);
}
// bf16 pack/unpack (truncation; bias cancels in the lh ratio)
__device__ __forceinline__ uint pk_bf16(float lo, float hi){
    return (__builtin_bit_cast(uint, hi) & 0xFFFF0000u)
         | (__builtin_bit_cast(uint, lo) >> 16);
}
__device__ __forceinline__ float up_lo(uint u){ return __builtin_bit_cast(float, u << 16); }
__device__ __forceinline__ float up_hi(uint u){ return __builtin_bit_cast(float, u & 0xFFFF0000u); }
__device__ __forceinline__ float up_us(ushort u){ return __builtin_bit_cast(float, ((uint)u) << 16); }
// ---- fp64 DPP (final reductions only) ----
template<int CTRL>
__device__ __forceinline__ double dpp0_f64(double x){
    int2 v = __builtin_bit_cast(int2, x);
    int2 r;
    r.x = __builtin_amdgcn_update_dpp(0, v.x, CTRL, 0xF, 0xF, true);
    r.y = __builtin_amdgcn_update_dpp(0, v.y, CTRL, 0xF, 0xF, true);
    return __builtin_bit_cast(double, r);
}
__device__ __forceinline__ double full64d(double x){
    x += dpp0_f64<0x111>(x); x += dpp0_f64<0x112>(x); x += dpp0_f64<0x114>(x);
    x += dpp0_f64<0x118>(x); x += dpp0_f64<0x142>(x); x += dpp0_f64<0x143>(x);
    return x;
}

// =================== row-storing scan (both roles, bf16 rows) ===================
template<bool REV>
__device__ __forceinline__ void scan_body(
    int b, int l, const float* __restrict__ P, const int* __restrict__ seqg,
    int blank, ushort* __restrict__ W, ushort* __restrict__ W4,
    int* __restrict__ Eb)
{
    const bool is63 = (l == 63);
    const float* Pb = P + (size_t)b * (CC*TT);
    const int* sq = seqg + b*SS;

    int r1, r3; float m1, m3;
    if (!REV) {
        r1 = sq[2*l]; r3 = sq[2*l+1];
        int ip = (l==0) ? 0 : (2*l-1);
        m1 = (l==0) ? 1.f : ((r1 != sq[ip]) ? 1.f : 0.f);
        m3 = (r3 != r1) ? 1.f : 0.f;
    } else {
        r1 = sq[SS-1-2*l]; r3 = sq[SS-2-2*l];
        int ip = (l==0) ? 0 : (SS-2*l);
        m1 = (l==0) ? 1.f : ((r1 != sq[ip]) ? 1.f : 0.f);
        m3 = (r3 != r1) ? 1.f : 0.f;
    }
    const float* pBp = Pb + (size_t)blank*TT;
    const float* p1p = Pb + (size_t)r1*TT;
    const float* p3p = Pb + (size_t)r3*TT;
    ushort* Ww  = W  + (size_t)b*TT*LPADH;
    ushort* W4b = W4 + (size_t)b*TT;
    int* EbB = Eb + b*64;

    // start-mask thresholds: state s masked at step i iff i >= (s+769)>>1
    const int tm0=(4*l+769)>>1, tm1=(4*l+770)>>1, tm2=(4*l+771)>>1, tm3=(4*l+772)>>1;

    float pbB[8], pb1[8], pb3[8];
    #pragma unroll
    for (int j=0;j<8;++j){
        int pc = REV ? (TT-1-j) : j;
        pbB[j]=pBp[pc]; pb1[j]=p1p[pc]; pb3[j]=p3p[pc];
    }

    float a0=0.f,a1=0.f,a2=0.f,a3=0.f,a4=0.f;
    float scNext = 1.f, Sfull = 0.f;
    const float u0i = (l==0) ? 1.f : 0.f;
    // group store buffer (static-indexed -> registers)
    uint sbLo[8], sbHi[8]; float s4f[8];

#define STEP(i, j, FIRSTF, MASKF)                                           \
  {                                                                         \
    float u0,u1,u2,u3,u4;                                                   \
    if (FIRSTF) { u0=u0i; u1=u0i; u2=0.f; u3=0.f; u4=0.f; }                 \
    else {                                                                  \
      float e3u = shfl_up1_f32(a3);                                         \
      u0 = a0 + e3u; u1 = (a1+a0) + m1*e3u; u2 = a2+a1;                     \
      u3 = (a3+a2) + m3*a1; u4 = a4+a3;                                     \
      if (MASKF) {                                                          \
        if ((i) >= tm0) u0 = 0.f;                                           \
        if ((i) >= tm1) u1 = 0.f;                                           \
        if ((i) >= tm2) u2 = 0.f;                                           \
        if ((i) >= tm3) u3 = 0.f;                                           \
      }                                                                     \
    }                                                                       \
    float pB=pbB[j], pq=pb1[j], pr=pb3[j];                                  \
    if ((j)==0) { pB*=scNext; pq*=scNext; pr*=scNext; }                     \
    float n0=u0*pB, n1=u1*pq, n2=u2*pB, n3=u3*pr, n4=u4*pB;                 \
    sbLo[j]=pk_bf16(n0,n1); sbHi[j]=pk_bf16(n2,n3); s4f[j]=n4;              \
    if ((j)==5) {                                                           \
      float part=(n0+n1)+(n2+n3); if (is63) part+=n4;                       \
      Sfull = full64f(part);                                                \
    }                                                                       \
    if ((j)==7) {                                                           \
      float Su = readlane63_f32(Sfull);                                     \
      int ex = (__builtin_bit_cast(int, Su) >> 23) & 0xFF;                  \
      int e = (ex==0) ? 0 : (ex-127);                                       \
      e = e < -120 ? -120 : (e > 120 ? 120 : e);                            \
      scNext = pow2if(-e);                                                  \
      if (REV && l==0 && (i)+1 < TT) EbB[((i)+1)>>3] = e;                   \
    }                                                                       \
    a0=n0; a1=n1; a2=n2; a3=n3; a4=n4;                                      \
    int inx = ((i)+8 < TT) ? (i)+8 : TT-1;                                  \
    int pcn = REV ? (TT-1-inx) : inx;                                       \
    pbB[j]=pBp[pcn]; pb1[j]=p1p[pcn]; pb3[j]=p3p[pcn];                      \
  }

#define GSTORE(i0)                                                          \
  {                                                                         \
    _Pragma("unroll")                                                       \
    for (int j=0;j<8;++j)                                                   \
      *reinterpret_cast<uint2*>(Ww + (size_t)j*LPADH + 4*l)                 \
          = make_uint2(sbLo[j], sbHi[j]);                                   \
    if (is63) {                                                             \
      uint4 pk;                                                             \
      pk.x = pk_bf16(s4f[0], s4f[1]);                                       \
      pk.y = pk_bf16(s4f[2], s4f[3]);                                       \
      pk.z = pk_bf16(s4f[4], s4f[5]);                                       \
      pk.w = pk_bf16(s4f[6], s4f[7]);                                       \
      *reinterpret_cast<uint4*>(W4b + (i0)) = pk;                           \
    }                                                                       \
    Ww += 8*LPADH;                                                          \
  }

    STEP(0,0,true,false)  STEP(1,1,false,false) STEP(2,2,false,false)
    STEP(3,3,false,false) STEP(4,4,false,false) STEP(5,5,false,false)
    STEP(6,6,false,false) STEP(7,7,false,false)
    GSTORE(0)
    for (int i0=8; i0<TT-SS; i0+=8) {
        #pragma unroll
        for (int j=0;j<8;++j) STEP(i0+j, j, false, false)
        GSTORE(i0)
    }
    for (int i0=TT-SS; i0<TT; i0+=8) {
        #pragma unroll
        for (int j=0;j<8;++j) STEP(i0+j, j, false, true)
        GSTORE(i0)
    }
#undef STEP
#undef GSTORE
}

__global__ __launch_bounds__(64)
void ctc_scan(const float* __restrict__ P, const int* __restrict__ seqg,
              const int* __restrict__ blankp, ushort* __restrict__ Wa,
              ushort* __restrict__ Wb, ushort* __restrict__ W4a,
              ushort* __restrict__ W4b, int* __restrict__ Eb)
{
    const int bx = blockIdx.x, l = threadIdx.x;
    const int blank = blankp[0];
    if (bx < BB) scan_body<false>(bx,      l, P, seqg, blank, Wa, W4a, Eb);
    else         scan_body<true >(bx - BB, l, P, seqg, blank, Wb, W4b, Eb);
}

// =========================== parallel combine ===========================
// Block (b, q): one wave handles t = 8q .. 8q+7.  i = T-1-t.
__global__ __launch_bounds__(64)
void ctc_combine(const ushort* __restrict__ Wa, const ushort* __restrict__ Wb,
                 const ushort* __restrict__ W4a, const ushort* __restrict__ W4b,
                 const int* __restrict__ Eb, const int* __restrict__ seqg,
                 double* __restrict__ Lq)
{
    const int b = blockIdx.x, q = blockIdx.y, l = threadIdx.x;
    const bool is63 = (l == 63);
    const int* sq = seqg + b*SS;
    // beta-orientation skip masks (same as the beta scan)
    const int r1 = sq[SS-1-2*l], r3 = sq[SS-2-2*l];
    const int ip = (l==0) ? 0 : (SS-2*l);
    const float m1 = (l==0) ? 1.f : ((r1 != sq[ip]) ? 1.f : 0.f);
    const float m3 = (r3 != r1) ? 1.f : 0.f;
    const int tm0=(4*l+769)>>1, tm1=(4*l+770)>>1, tm2=(4*l+771)>>1, tm3=(4*l+772)>>1;

    const ushort* WaB = Wa + (size_t)b*TT*LPADH;
    const ushort* WbB = Wb + (size_t)b*TT*LPADH;
    const ushort* W4aB = W4a + (size_t)b*TT;
    const ushort* W4bB = W4b + (size_t)b*TT;
    const int t0 = q*8;

    // preload R for the first step: R_i0 = sum of w_b row i0 = T-1-t0
    float Rcur;
    {
        const ushort* rw = WbB + (size_t)(TT-1-t0)*LPADH;
        uint2 xu = *reinterpret_cast<const uint2*>(rw + 4*l);
        float rnp = (up_lo(xu.x)+up_hi(xu.x))+(up_lo(xu.y)+up_hi(xu.y));
        if (is63) rnp += up_us(W4bB[TT-1-t0]);
        Rcur = full64f(rnp);          // valid on lane 63 (consumed there)
    }
    double acc = 0.0;

    #pragma unroll
    for (int k=0; k<8; ++k) {
        const int t = t0 + k;
        const int i = TT-1-t;
        // alpha row t, reversed fragment: lane l holds w_a[252-4l .. 255-4l];
        // the 5th element w_a[256-4l] = neighbor's av0 (DPP), lane0 = row[256]
        const ushort* arow = WaB + (size_t)t*LPADH;
        uint2 au = *reinterpret_cast<const uint2*>(arow + (252 - 4*l));
        float av0 = up_lo(au.x), av1 = up_hi(au.x);
        float av2 = up_lo(au.y), av3 = up_hi(au.y);
        float a256 = up_us(W4aB[t]);                // uniform
        float ar4 = shfl_up1_f32(av0);
        if (l == 0) ar4 = a256;

        float u0,u1,u2,u3,u4, rnext = 0.f;
        if (i > 0) {
            const ushort* rw = WbB + (size_t)(i-1)*LPADH;
            uint2 bu = *reinterpret_cast<const uint2*>(rw + 4*l);
            float bv0 = up_lo(bu.x), bv1 = up_hi(bu.x);
            float bv2 = up_lo(bu.y), bv3 = up_hi(bu.y);
            float b4 = up_us(W4bB[i-1]);            // uniform broadcast
            float e3u = shfl_up1_f32(bv3);          // w_b[4l-1]
            u0 = bv0 + e3u;
            u1 = (bv1 + bv0) + m1*e3u;
            u2 = bv2 + bv1;
            u3 = (bv3 + bv2) + m3*bv1;
            u4 = b4 + bv3;                          // s'=256 (lane 63)
            if (i >= TT - SS) {
                if (i >= tm0) u0 = 0.f;
                if (i >= tm1) u1 = 0.f;
                if (i >= tm2) u2 = 0.f;
                if (i >= tm3) u3 = 0.f;
            }
            rnext = (bv0+bv1)+(bv2+bv3);            // R_{i-1} partial
            if (is63) rnext += b4;
        } else {
            u0 = (l==0)?1.f:0.f; u1 = u0; u2=0.f; u3=0.f; u4=0.f;
        }
        // D = sum_s' w_a[256-s',t]*U[s'] ; S = sum w_a row t
        float trp = ar4*u0 + av3*u1 + av2*u2 + av1*u3;
        if (is63) trp += av0*u4;
        float sap = (av1 + av2) + (av3 + ar4);
        if (is63) sap += av0;

        float D  = full64f(trp);
        float S  = full64f(sap);
        float Rn = full64f(rnext);
        if (is63) {
            double e = (i > 0 && (i & 7) == 0) ? (double)Eb[b*64 + (i>>3)] : 0.0;
            double dd = fmax((double)D, 1e-300);
            double sr = fmax((double)S * (double)Rcur, 1e-300);
            acc += log(dd) - log(sr) - e*M_LN2;
        }
        Rcur = Rn;   // lane-63-valid, lane-63-consumed
    }
    if (is63) Lq[b*64 + q] = acc;
}

__global__ __launch_bounds__(256)
void ctc_final(const double* __restrict__ Lq, float* __restrict__ out)
{
    const int t = threadIdx.x;        // 256 threads, 8192 inputs
    double v = 0.0;
    #pragma unroll
    for (int k=0;k<32;++k) v += Lq[t + 256*k];
    double s = full64d(v);
    __shared__ double w[4];
    if ((t & 63) == 63) w[t>>6] = s;
    __syncthreads();
    if (t == 0) out[0] = (float)(-(w[0]+w[1]+w[2]+w[3]));
}

extern "C" void kernel_launch(void* const* d_in, const int* in_sizes, int n_in,
                              void* d_out, int out_size, void* d_ws, size_t ws_size,
                              hipStream_t stream)
{
    const float* P     = (const float*)d_in[0];   // params (B,C,T) fp32
    const int*   seq   = (const int*)  d_in[1];   // (B,S) int32
    // d_in[2] = lengths (unused by the reference computation)
    const int*   blank = (const int*)  d_in[3];   // scalar int

    // ws layout (bf16 rows): Wa | Wb (34.1 MB each) | W4a | W4b | Lq | Eb
    ushort* Wa  = (ushort*)d_ws;
    ushort* Wb  = Wa  + (size_t)BB*TT*LPADH;
    ushort* W4a = Wb  + (size_t)BB*TT*LPADH;      // BB*TT ushorts (128 KB)
    ushort* W4b = W4a + (size_t)BB*TT;
    double* Lq  = (double*)(W4b + (size_t)BB*TT); // 8192 doubles
    int*    Eb  = (int*)(Lq + (size_t)BB*64);     // 8192 ints
    (void)ws_size; (void)in_sizes; (void)n_in; (void)out_size;

    ctc_scan<<<2*BB, 64, 0, stream>>>(P, seq, blank, Wa, Wb, W4a, W4b, Eb);
    ctc_combine<<<dim3(BB, 64), 64, 0, stream>>>(Wa, Wb, W4a, W4b, Eb, seq, Lq);
    ctc_final<<<1, 256, 0, stream>>>(Lq, (float*)d_out);
}

// Round 10
// 79.514 us; speedup vs baseline: 1.1304x; 1.0012x over previous
//
#include <hip/hip_runtime.h>
#include <math.h>

// CTC loss (per-step-normalized fwd/bwd), B=128, C=512, T=512, S=128, L=257.
// Round-10: single change vs round-9 -- __launch_bounds__(64, 1) on the scan.
// Diagnosis: scan VGPR_Count=36 (r5/r6 profiles) proves the allocator, tuned
// for default occupancy, collapsed the written 8-step p-prefetch to just-
// before-use loads -> ~250 cy of raw L2/L3 latency per step, invariant to
// store batching (r7), gather batching (r8), and fp64->fp32 (r4 vs r6) --
// the only model consistent with all four null results. min-waves=1 frees
// up to 512 VGPRs so the prefetch can actually stay in flight.
// Identity (validated r4-r9):  lh_t = sigma_i * D / (S_t * R_i), i = T-1-t,
//   D = sum_s' w_a[256-s',t] * U_i[s'],  U_i = masked shift of w_b row i-1,
//   S_t = sum w_a row t, R_i = sum w_b row i, sigma_i = 2^-e_g at i=8g.
// bf16 rows (truncation bias cancels in the lh ratio); fp64 log accumulation.
// All quantities >= 0 and finite; logs clamped -> no NaN possible.

#define BB 128
#define CC 512
#define TT 512
#define SS 128
#define LL 257
#define LPADH 260   // bf16 (ushort) elements per row = 520 B, 8B-aligned slots

typedef unsigned int  uint;
typedef unsigned short ushort;

// ---- fp32 DPP helpers (gfx9 controls; validated on gfx950 rounds 3-9) ----
template<int CTRL>
__device__ __forceinline__ float dpp0_f32(float x){
    int v = __builtin_bit_cast(int, x);
    int r = __builtin_amdgcn_update_dpp(0, v, CTRL, 0xF, 0xF, true);
    return __builtin_bit_cast(float, r);
}
__device__ __forceinline__ float shfl_up1_f32(float x){ return dpp0_f32<0x138>(x); }
__device__ __forceinline__ float red8f(float x){
    x += dpp0_f32<0x111>(x);  // row_shr:1
    x += dpp0_f32<0x112>(x);  // row_shr:2
    x += dpp0_f32<0x114>(x);  // row_shr:4
    return x;
}
__device__ __forceinline__ float tail3f(float x){   // full 64-lane sum -> lane 63
    x += dpp0_f32<0x118>(x);  // row_shr:8
    x += dpp0_f32<0x142>(x);  // row_bcast:15
    x += dpp0_f32<0x143>(x);  // row_bcast:31
    return x;
}
__device__ __forceinline__ float full64f(float x){ return tail3f(red8f(x)); }
__device__ __forceinline__ float readlane63_f32(float x){
    int v = __builtin_bit_cast(int, x);
    return __builtin_bit_cast(float, __builtin_amdgcn_readlane(v, 63));
}
__device__ __forceinline__ float pow2if(int e){     // e in [-126,127], exact
    return __builtin_bit_cast(float, (127 + e) << 23);
}
// bf16 pack/unpack (truncation; bias cancels in the lh ratio)
__device__ __forceinline__ uint pk_bf16(float lo, float hi){
    return (__builtin_bit_cast(uint, hi) & 0xFFFF0000u)
         | (__builtin_bit_cast(uint, lo) >> 16);
}
__device__ __forceinline__ float up_lo(uint u){ return __builtin_bit_cast(float, u << 16); }
__device__ __forceinline__ float up_hi(uint u){ return __builtin_bit_cast(float, u & 0xFFFF0000u); }
__device__ __forceinline__ float up_us(ushort u){ return __builtin_bit_cast(float, ((uint)u) << 16); }
// ---- fp64 DPP (final reductions only) ----
template<int CTRL>
__device__ __forceinline__ double dpp0_f64(double x){
    int2 v = __builtin_bit_cast(int2, x);
    int2 r;
    r.x = __builtin_amdgcn_update_dpp(0, v.x, CTRL, 0xF, 0xF, true);
    r.y = __builtin_amdgcn_update_dpp(0, v.y, CTRL, 0xF, 0xF, true);
    return __builtin_bit_cast(double, r);
}
__device__ __forceinline__ double full64d(double x){
    x += dpp0_f64<0x111>(x); x += dpp0_f64<0x112>(x); x += dpp0_f64<0x114>(x);
    x += dpp0_f64<0x118>(x); x += dpp0_f64<0x142>(x); x += dpp0_f64<0x143>(x);
    return x;
}

// =================== row-storing scan (both roles, bf16 rows) ===================
template<bool REV>
__device__ __forceinline__ void scan_body(
    int b, int l, const float* __restrict__ P, const int* __restrict__ seqg,
    int blank, ushort* __restrict__ W, ushort* __restrict__ W4,
    int* __restrict__ Eb)
{
    const bool is63 = (l == 63);
    const float* Pb = P + (size_t)b * (CC*TT);
    const int* sq = seqg + b*SS;

    int r1, r3; float m1, m3;
    if (!REV) {
        r1 = sq[2*l]; r3 = sq[2*l+1];
        int ip = (l==0) ? 0 : (2*l-1);
        m1 = (l==0) ? 1.f : ((r1 != sq[ip]) ? 1.f : 0.f);
        m3 = (r3 != r1) ? 1.f : 0.f;
    } else {
        r1 = sq[SS-1-2*l]; r3 = sq[SS-2-2*l];
        int ip = (l==0) ? 0 : (SS-2*l);
        m1 = (l==0) ? 1.f : ((r1 != sq[ip]) ? 1.f : 0.f);
        m3 = (r3 != r1) ? 1.f : 0.f;
    }
    const float* pBp = Pb + (size_t)blank*TT;
    const float* p1p = Pb + (size_t)r1*TT;
    const float* p3p = Pb + (size_t)r3*TT;
    ushort* Ww  = W  + (size_t)b*TT*LPADH;
    ushort* W4b = W4 + (size_t)b*TT;
    int* EbB = Eb + b*64;

    // start-mask thresholds: state s masked at step i iff i >= (s+769)>>1
    const int tm0=(4*l+769)>>1, tm1=(4*l+770)>>1, tm2=(4*l+771)>>1, tm3=(4*l+772)>>1;

    float pbB[8], pb1[8], pb3[8];
    #pragma unroll
    for (int j=0;j<8;++j){
        int pc = REV ? (TT-1-j) : j;
        pbB[j]=pBp[pc]; pb1[j]=p1p[pc]; pb3[j]=p3p[pc];
    }

    float a0=0.f,a1=0.f,a2=0.f,a3=0.f,a4=0.f;
    float scNext = 1.f, Sfull = 0.f;
    const float u0i = (l==0) ? 1.f : 0.f;
    // group store buffer (static-indexed -> registers)
    uint sbLo[8], sbHi[8]; float s4f[8];

#define STEP(i, j, FIRSTF, MASKF)                                           \
  {                                                                         \
    float u0,u1,u2,u3,u4;                                                   \
    if (FIRSTF) { u0=u0i; u1=u0i; u2=0.f; u3=0.f; u4=0.f; }                 \
    else {                                                                  \
      float e3u = shfl_up1_f32(a3);                                         \
      u0 = a0 + e3u; u1 = (a1+a0) + m1*e3u; u2 = a2+a1;                     \
      u3 = (a3+a2) + m3*a1; u4 = a4+a3;                                     \
      if (MASKF) {                                                          \
        if ((i) >= tm0) u0 = 0.f;                                           \
        if ((i) >= tm1) u1 = 0.f;                                           \
        if ((i) >= tm2) u2 = 0.f;                                           \
        if ((i) >= tm3) u3 = 0.f;                                           \
      }                                                                     \
    }                                                                       \
    float pB=pbB[j], pq=pb1[j], pr=pb3[j];                                  \
    if ((j)==0) { pB*=scNext; pq*=scNext; pr*=scNext; }                     \
    float n0=u0*pB, n1=u1*pq, n2=u2*pB, n3=u3*pr, n4=u4*pB;                 \
    sbLo[j]=pk_bf16(n0,n1); sbHi[j]=pk_bf16(n2,n3); s4f[j]=n4;              \
    if ((j)==5) {                                                           \
      float part=(n0+n1)+(n2+n3); if (is63) part+=n4;                       \
      Sfull = full64f(part);                                                \
    }                                                                       \
    if ((j)==7) {                                                           \
      float Su = readlane63_f32(Sfull);                                     \
      int ex = (__builtin_bit_cast(int, Su) >> 23) & 0xFF;                  \
      int e = (ex==0) ? 0 : (ex-127);                                       \
      e = e < -120 ? -120 : (e > 120 ? 120 : e);                            \
      scNext = pow2if(-e);                                                  \
      if (REV && l==0 && (i)+1 < TT) EbB[((i)+1)>>3] = e;                   \
    }                                                                       \
    a0=n0; a1=n1; a2=n2; a3=n3; a4=n4;                                      \
    int inx = ((i)+8 < TT) ? (i)+8 : TT-1;                                  \
    int pcn = REV ? (TT-1-inx) : inx;                                       \
    pbB[j]=pBp[pcn]; pb1[j]=p1p[pcn]; pb3[j]=p3p[pcn];                      \
  }

#define GSTORE(i0)                                                          \
  {                                                                         \
    _Pragma("unroll")                                                       \
    for (int j=0;j<8;++j)                                                   \
      *reinterpret_cast<uint2*>(Ww + (size_t)j*LPADH + 4*l)                 \
          = make_uint2(sbLo[j], sbHi[j]);                                   \
    if (is63) {                                                             \
      uint4 pk;                                                             \
      pk.x = pk_bf16(s4f[0], s4f[1]);                                       \
      pk.y = pk_bf16(s4f[2], s4f[3]);                                       \
      pk.z = pk_bf16(s4f[4], s4f[5]);                                       \
      pk.w = pk_bf16(s4f[6], s4f[7]);                                       \
      *reinterpret_cast<uint4*>(W4b + (i0)) = pk;                           \
    }                                                                       \
    Ww += 8*LPADH;                                                          \
  }

    STEP(0,0,true,false)  STEP(1,1,false,false) STEP(2,2,false,false)
    STEP(3,3,false,false) STEP(4,4,false,false) STEP(5,5,false,false)
    STEP(6,6,false,false) STEP(7,7,false,false)
    GSTORE(0)
    for (int i0=8; i0<TT-SS; i0+=8) {
        #pragma unroll
        for (int j=0;j<8;++j) STEP(i0+j, j, false, false)
        GSTORE(i0)
    }
    for (int i0=TT-SS; i0<TT; i0+=8) {
        #pragma unroll
        for (int j=0;j<8;++j) STEP(i0+j, j, false, true)
        GSTORE(i0)
    }
#undef STEP
#undef GSTORE
}

__global__ __launch_bounds__(64, 1)   // min 1 wave/EU -> full VGPR budget
void ctc_scan(const float* __restrict__ P, const int* __restrict__ seqg,
              const int* __restrict__ blankp, ushort* __restrict__ Wa,
              ushort* __restrict__ Wb, ushort* __restrict__ W4a,
              ushort* __restrict__ W4b, int* __restrict__ Eb)
{
    const int bx = blockIdx.x, l = threadIdx.x;
    const int blank = blankp[0];
    if (bx < BB) scan_body<false>(bx,      l, P, seqg, blank, Wa, W4a, Eb);
    else         scan_body<true >(bx - BB, l, P, seqg, blank, Wb, W4b, Eb);
}

// =========================== parallel combine ===========================
// Block (b, q): one wave handles t = 8q .. 8q+7.  i = T-1-t.
__global__ __launch_bounds__(64)
void ctc_combine(const ushort* __restrict__ Wa, const ushort* __restrict__ Wb,
                 const ushort* __restrict__ W4a, const ushort* __restrict__ W4b,
                 const int* __restrict__ Eb, const int* __restrict__ seqg,
                 double* __restrict__ Lq)
{
    const int b = blockIdx.x, q = blockIdx.y, l = threadIdx.x;
    const bool is63 = (l == 63);
    const int* sq = seqg + b*SS;
    // beta-orientation skip masks (same as the beta scan)
    const int r1 = sq[SS-1-2*l], r3 = sq[SS-2-2*l];
    const int ip = (l==0) ? 0 : (SS-2*l);
    const float m1 = (l==0) ? 1.f : ((r1 != sq[ip]) ? 1.f : 0.f);
    const float m3 = (r3 != r1) ? 1.f : 0.f;
    const int tm0=(4*l+769)>>1, tm1=(4*l+770)>>1, tm2=(4*l+771)>>1, tm3=(4*l+772)>>1;

    const ushort* WaB = Wa + (size_t)b*TT*LPADH;
    const ushort* WbB = Wb + (size_t)b*TT*LPADH;
    const ushort* W4aB = W4a + (size_t)b*TT;
    const ushort* W4bB = W4b + (size_t)b*TT;
    const int t0 = q*8;

    // preload R for the first step: R_i0 = sum of w_b row i0 = T-1-t0
    float Rcur;
    {
        const ushort* rw = WbB + (size_t)(TT-1-t0)*LPADH;
        uint2 xu = *reinterpret_cast<const uint2*>(rw + 4*l);
        float rnp = (up_lo(xu.x)+up_hi(xu.x))+(up_lo(xu.y)+up_hi(xu.y));
        if (is63) rnp += up_us(W4bB[TT-1-t0]);
        Rcur = full64f(rnp);          // valid on lane 63 (consumed there)
    }
    double acc = 0.0;

    #pragma unroll
    for (int k=0; k<8; ++k) {
        const int t = t0 + k;
        const int i = TT-1-t;
        // alpha row t, reversed fragment: lane l holds w_a[252-4l .. 255-4l];
        // the 5th element w_a[256-4l] = neighbor's av0 (DPP), lane0 = row[256]
        const ushort* arow = WaB + (size_t)t*LPADH;
        uint2 au = *reinterpret_cast<const uint2*>(arow + (252 - 4*l));
        float av0 = up_lo(au.x), av1 = up_hi(au.x);
        float av2 = up_lo(au.y), av3 = up_hi(au.y);
        float a256 = up_us(W4aB[t]);                // uniform
        float ar4 = shfl_up1_f32(av0);
        if (l == 0) ar4 = a256;

        float u0,u1,u2,u3,u4, rnext = 0.f;
        if (i > 0) {
            const ushort* rw = WbB + (size_t)(i-1)*LPADH;
            uint2 bu = *reinterpret_cast<const uint2*>(rw + 4*l);
            float bv0 = up_lo(bu.x), bv1 = up_hi(bu.x);
            float bv2 = up_lo(bu.y), bv3 = up_hi(bu.y);
            float b4 = up_us(W4bB[i-1]);            // uniform broadcast
            float e3u = shfl_up1_f32(bv3);          // w_b[4l-1]
            u0 = bv0 + e3u;
            u1 = (bv1 + bv0) + m1*e3u;
            u2 = bv2 + bv1;
            u3 = (bv3 + bv2) + m3*bv1;
            u4 = b4 + bv3;                          // s'=256 (lane 63)
            if (i >= TT - SS) {
                if (i >= tm0) u0 = 0.f;
                if (i >= tm1) u1 = 0.f;
                if (i >= tm2) u2 = 0.f;
                if (i >= tm3) u3 = 0.f;
            }
            rnext = (bv0+bv1)+(bv2+bv3);            // R_{i-1} partial
            if (is63) rnext += b4;
        } else {
            u0 = (l==0)?1.f:0.f; u1 = u0; u2=0.f; u3=0.f; u4=0.f;
        }
        // D = sum_s' w_a[256-s',t]*U[s'] ; S = sum w_a row t
        float trp = ar4*u0 + av3*u1 + av2*u2 + av1*u3;
        if (is63) trp += av0*u4;
        float sap = (av1 + av2) + (av3 + ar4);
        if (is63) sap += av0;

        float D  = full64f(trp);
        float S  = full64f(sap);
        float Rn = full64f(rnext);
        if (is63) {
            double e = (i > 0 && (i & 7) == 0) ? (double)Eb[b*64 + (i>>3)] : 0.0;
            double dd = fmax((double)D, 1e-300);
            double sr = fmax((double)S * (double)Rcur, 1e-300);
            acc += log(dd) - log(sr) - e*M_LN2;
        }
        Rcur = Rn;   // lane-63-valid, lane-63-consumed
    }
    if (is63) Lq[b*64 + q] = acc;
}

__global__ __launch_bounds__(256)
void ctc_final(const double* __restrict__ Lq, float* __restrict__ out)
{
    const int t = threadIdx.x;        // 256 threads, 8192 inputs
    double v = 0.0;
    #pragma unroll
    for (int k=0;k<32;++k) v += Lq[t + 256*k];
    double s = full64d(v);
    __shared__ double w[4];
    if ((t & 63) == 63) w[t>>6] = s;
    __syncthreads();
    if (t == 0) out[0] = (float)(-(w[0]+w[1]+w[2]+w[3]));
}

extern "C" void kernel_launch(void* const* d_in, const int* in_sizes, int n_in,
                              void* d_out, int out_size, void* d_ws, size_t ws_size,
                              hipStream_t stream)
{
    const float* P     = (const float*)d_in[0];   // params (B,C,T) fp32
    const int*   seq   = (const int*)  d_in[1];   // (B,S) int32
    // d_in[2] = lengths (unused by the reference computation)
    const int*   blank = (const int*)  d_in[3];   // scalar int

    // ws layout (bf16 rows): Wa | Wb (34.1 MB each) | W4a | W4b | Lq | Eb
    ushort* Wa  = (ushort*)d_ws;
    ushort* Wb  = Wa  + (size_t)BB*TT*LPADH;
    ushort* W4a = Wb  + (size_t)BB*TT*LPADH;      // BB*TT ushorts (128 KB)
    ushort* W4b = W4a + (size_t)BB*TT;
    double* Lq  = (double*)(W4b + (size_t)BB*TT); // 8192 doubles
    int*    Eb  = (int*)(Lq + (size_t)BB*64);     // 8192 ints
    (void)ws_size; (void)in_sizes; (void)n_in; (void)out_size;

    ctc_scan<<<2*BB, 64, 0, stream>>>(P, seq, blank, Wa, Wb, W4a, W4b, Eb);
    ctc_combine<<<dim3(BB, 64), 64, 0, stream>>>(Wa, Wb, W4a, W4b, Eb, seq, Lq);
    ctc_final<<<1, 256, 0, stream>>>(Lq, (float*)d_out);
}